// Round 1
// baseline (475.710 us; speedup 1.0000x reference)
//
#include <hip/hip_runtime.h>
#include <math.h>

#define NLk 3
#define NSTATE 65536          // 2^16
#define OUTSTRIDE 131328      // 2*65536 + 256

// One kernel, 64 blocks x 1024 threads.
//  blocks 0..31  : state-vector simulation for batch b (state held in registers)
//  blocks 32..63 : Hamiltonian MLP for batch b-32
// State mapping (sim blocks): amp index A = (wv<<12) | (reg<<6) | lane
//   bits 0..5  = lane      -> gates via __shfl_xor
//   bits 6..11 = reg index -> gates in registers
//   bits 12..15= wave id   -> gates via LDS exchange (128KB buffer, 2 chunks)
__global__ __launch_bounds__(1024) void vqe_fused(
    const float* __restrict__ coords, const float* __restrict__ feats,
    const float* __restrict__ rotp,   const float* __restrict__ entp,
    const float* __restrict__ fpw1,   const float* __restrict__ fpb1,
    const float* __restrict__ fpw2,   const float* __restrict__ fpb2,
    const float* __restrict__ hcw1,   const float* __restrict__ hcb1,
    const float* __restrict__ hcw2,   const float* __restrict__ hcb2,
    const float* __restrict__ hcw3,   const float* __restrict__ hcb3,
    float* __restrict__ out)
{
  __shared__ float s_x[32*1024];      // 128KB exchange buffer (aliased as MLP temp)
  __shared__ float s_pf[16];
  __shared__ float s_rot[NLk*16*4];   // r00,r01,r10,r11 per (layer,qubit)
  __shared__ float s_ent[NLk*15];     // sigmoid(ent)

  const int tid = threadIdx.x;
  const int bid = blockIdx.x;

  if (bid >= 32) {
    // ---------------- Hamiltonian block ----------------
    const int b = bid - 32;
    float* xh = s_x;          // 60
    float* h1 = s_x + 64;     // 256
    float* h2 = s_x + 384;    // 128
    float* h3 = s_x + 512;    // 256
    if (tid < 60) xh[tid] = coords[b*60 + tid];
    __syncthreads();
    if (tid < 256) {
      float acc = hcb1[tid];
      const float* w = hcw1 + tid*60;
      for (int k = 0; k < 60; ++k) acc += w[k]*xh[k];
      h1[tid] = fmaxf(acc, 0.f);
    }
    __syncthreads();
    if (tid < 128) {
      float acc = hcb2[tid];
      const float* w = hcw2 + tid*256;
      for (int k = 0; k < 256; ++k) acc += w[k]*h1[k];
      h2[tid] = fmaxf(acc, 0.f);
    }
    __syncthreads();
    if (tid < 256) {
      float acc = hcb3[tid];
      const float* w = hcw3 + tid*128;
      for (int k = 0; k < 128; ++k) acc += w[k]*h2[k];
      h3[tid] = acc;
    }
    __syncthreads();
    if (tid < 256) {
      float s = 0.f, sq = 0.f;
      for (int k = 0; k < 60; ++k) { float v = xh[k]; s += v; sq += v*v; }
      float mean = s * (1.f/60.f);
      float var  = (sq - 60.f*mean*mean) * (1.f/59.f);
      float freq = sqrtf(1.f/(var + 1e-6f)) * 200.f;
      int i = tid >> 4, j = tid & 15;
      float v = 0.5f*(h3[tid] + h3[j*16 + i]) + ((i==j) ? freq : 0.f);
      out[(size_t)b*OUTSTRIDE + 2*NSTATE + tid] = v;
    }
    return;
  }

  // ---------------- Simulation block ----------------
  const int b    = bid;
  const int lane = tid & 63;
  const int wv   = tid >> 6;

  // Phase 0a: feature-MLP hidden layer (64) + entangler sigmoids (45)
  if (tid < 64) {
    float acc = fpb1[tid];
    const float* w = fpw1 + tid*100;
    const float* f = feats + b*100;
    for (int k = 0; k < 100; ++k) acc += w[k]*f[k];
    s_x[tid] = fmaxf(acc, 0.f);
  } else if (tid < 64+45) {
    int c = tid - 64;
    s_ent[c] = 1.f / (1.f + expf(-entp[c]));
  }
  __syncthreads();
  // Phase 0b: pf = tanh(h1 @ w2^T + b2)
  if (tid < 16) {
    float acc = fpb2[tid];
    const float* w = fpw2 + tid*64;
    for (int k = 0; k < 64; ++k) acc += w[k]*s_x[k];
    s_pf[tid] = tanhf(acc);
  }
  __syncthreads();
  // Phase 0c: rotation matrices (row0=[cxcycz,-sxsysz], row1=[sxsycz,cxcysz])
  if (tid < 48) {                       // tid = layer*16 + q
    float ang = s_pf[tid & 15];
    const float* rp = rotp + tid*3;
    float cx = cosf(0.5f*rp[0]*ang), sx = sinf(0.5f*rp[0]*ang);
    float cy = cosf(0.5f*rp[1]*ang), sy = sinf(0.5f*rp[1]*ang);
    float cz = cosf(0.5f*rp[2]*ang), sz = sinf(0.5f*rp[2]*ang);
    s_rot[tid*4+0] =  cx*cy*cz;
    s_rot[tid*4+1] = -sx*sy*sz;
    s_rot[tid*4+2] =  sx*sy*cz;
    s_rot[tid*4+3] =  cx*cy*sz;
  }
  __syncthreads();

  // State: 64 amplitudes per thread, in registers.
  float a[64];
  #pragma unroll
  for (int i = 0; i < 64; ++i) a[i] = 0.f;
  if (tid == 0) a[0] = 1.f;

  #pragma unroll 1
  for (int lay = 0; lay < NLk; ++lay) {
    const float* rc = s_rot + lay*64;
    // ---- rotations q = 0..15 ----
    #pragma unroll
    for (int q = 0; q < 16; ++q) {
      const float r00 = rc[q*4+0], r01 = rc[q*4+1];
      const float r10 = rc[q*4+2], r11 = rc[q*4+3];
      if (q < 6) {
        // amp bit q lives in lane bits -> wave shuffle
        const int m   = 1 << q;
        const int bit = (lane >> q) & 1;
        const float cown = bit ? r11 : r00;
        const float coth = bit ? r10 : r01;
        #pragma unroll
        for (int i = 0; i < 64; ++i) {
          float o = __shfl_xor(a[i], m, 64);
          a[i] = cown*a[i] + coth*o;
        }
      } else if (q < 12) {
        // amp bit q lives in register index -> local pairs
        const int s = 1 << (q-6);
        #pragma unroll
        for (int i = 0; i < 64; ++i) {
          if (!(i & s)) {
            const int i1 = i | s;
            float a0 = a[i], a1 = a[i1];
            a[i]  = r00*a0 + r01*a1;
            a[i1] = r10*a0 + r11*a1;
          }
        }
      } else {
        // amp bit q lives in wave id -> LDS exchange (2 chunks of 32)
        const int k   = q - 12;
        const int bit = (wv >> k) & 1;
        const float cown = bit ? r11 : r00;
        const float coth = bit ? r10 : r01;
        const int pbase = ((wv ^ (1 << k)) << 6) | lane;
        #pragma unroll
        for (int ch = 0; ch < 2; ++ch) {
          __syncthreads();
          #pragma unroll
          for (int j = 0; j < 32; ++j) s_x[j*1024 + tid] = a[ch*32 + j];
          __syncthreads();
          #pragma unroll
          for (int j = 0; j < 32; ++j) {
            float o = s_x[j*1024 + pbase];
            a[ch*32+j] = cown*a[ch*32+j] + coth*o;
          }
        }
      }
    }
    // ---- entanglers c = 0..14 (ctrl=bit c, target=bit c+1) ----
    // new_t = t + p*(other - t) on both sides of the pair, only when ctrl==1
    const float* ec = s_ent + lay*15;
    #pragma unroll
    for (int c = 0; c < 15; ++c) {
      const float p = ec[c];
      if (c < 5) {
        // ctrl lane bit c, target lane bit c+1
        const float pe = ((lane >> c) & 1) ? p : 0.f;
        const int m = 2 << c;
        #pragma unroll
        for (int i = 0; i < 64; ++i) {
          float o = __shfl_xor(a[i], m, 64);
          a[i] += pe*(o - a[i]);
        }
      } else if (c == 5) {
        // ctrl lane bit 5, target reg bit 0
        const float pe = ((lane >> 5) & 1) ? p : 0.f;
        #pragma unroll
        for (int i = 0; i < 64; i += 2) {
          float d = pe*(a[i+1] - a[i]);
          a[i] += d; a[i+1] -= d;
        }
      } else if (c < 11) {
        // ctrl reg bit c-6, target reg bit c-5
        const int cb = 1 << (c-6), tb = 1 << (c-5);
        #pragma unroll
        for (int i = 0; i < 64; ++i) {
          if ((i & cb) && !(i & tb)) {
            const int i1 = i | tb;
            float d = p*(a[i1] - a[i]);
            a[i] += d; a[i1] -= d;
          }
        }
      } else if (c == 11) {
        // ctrl reg bit 5 (elements 32..63 only), target wave bit 0
        const int pbase = ((wv ^ 1) << 6) | lane;
        __syncthreads();
        #pragma unroll
        for (int j = 0; j < 32; ++j) s_x[j*1024 + tid] = a[32+j];
        __syncthreads();
        #pragma unroll
        for (int j = 0; j < 32; ++j) {
          float o = s_x[j*1024 + pbase];
          a[32+j] += p*(o - a[32+j]);
        }
      } else {
        // ctrl wave bit c-12, target wave bit c-11 (pairs share ctrl value)
        const int k  = c - 11;
        const int cb = (wv >> (c-12)) & 1;
        const int pbase = ((wv ^ (1 << k)) << 6) | lane;
        #pragma unroll
        for (int ch = 0; ch < 2; ++ch) {
          __syncthreads();
          if (cb) {
            #pragma unroll
            for (int j = 0; j < 32; ++j) s_x[j*1024 + tid] = a[ch*32+j];
          }
          __syncthreads();
          if (cb) {
            #pragma unroll
            for (int j = 0; j < 32; ++j) {
              float o = s_x[j*1024 + pbase];
              a[ch*32+j] += p*(o - a[ch*32+j]);
            }
          }
        }
      }
    }
  }

  // ---- epilogue: real amps + zero imag (state is provably real) ----
  {
    float* orr = out + (size_t)b*OUTSTRIDE;
    float* oii = orr + NSTATE;
    const int base = (wv << 12) | lane;
    #pragma unroll
    for (int i = 0; i < 64; ++i) {
      orr[base + (i<<6)] = a[i];
      oii[base + (i<<6)] = 0.f;
    }
  }
}

extern "C" void kernel_launch(void* const* d_in, const int* in_sizes, int n_in,
                              void* d_out, int out_size, void* d_ws, size_t ws_size,
                              hipStream_t stream) {
  vqe_fused<<<dim3(64), dim3(1024), 0, stream>>>(
      (const float*)d_in[0],  (const float*)d_in[1],
      (const float*)d_in[2],  (const float*)d_in[3],
      (const float*)d_in[4],  (const float*)d_in[5],
      (const float*)d_in[6],  (const float*)d_in[7],
      (const float*)d_in[8],  (const float*)d_in[9],
      (const float*)d_in[10], (const float*)d_in[11],
      (const float*)d_in[12], (const float*)d_in[13],
      (float*)d_out);
}

// Round 2
// 266.832 us; speedup vs baseline: 1.7828x; 1.7828x over previous
//
#include <hip/hip_runtime.h>
#include <math.h>

#define NLk 3
#define NSTATE 65536          // 2^16
#define OUTSTRIDE 131328      // 2*65536 + 256

// One kernel, 64 blocks x 1024 threads.
//  blocks 0..31  : state-vector simulation for batch b (state held in registers)
//  blocks 32..63 : Hamiltonian MLP for batch b-32
// State mapping (sim blocks): amp index A = (wv<<12) | (reg<<6) | lane
//   bits 0..5  = lane      -> gates via __shfl_xor
//   bits 6..11 = reg index -> gates in registers
//   bits 12..15= wave id   -> gates via LDS exchange (128KB float4 buffer, 2 chunks)
// __launch_bounds__(1024, 4): 16 waves/CU = 4 waves/SIMD -> 128 VGPR budget.
// Without the ",4" the compiler targeted 64 VGPRs and spilled a[64] (R1: 43MB
// of scratch HBM traffic, 476us).
__global__ __launch_bounds__(1024, 4) void vqe_fused(
    const float* __restrict__ coords, const float* __restrict__ feats,
    const float* __restrict__ rotp,   const float* __restrict__ entp,
    const float* __restrict__ fpw1,   const float* __restrict__ fpb1,
    const float* __restrict__ fpw2,   const float* __restrict__ fpb2,
    const float* __restrict__ hcw1,   const float* __restrict__ hcb1,
    const float* __restrict__ hcw2,   const float* __restrict__ hcb2,
    const float* __restrict__ hcw3,   const float* __restrict__ hcb3,
    float* __restrict__ out)
{
  __shared__ float4 s_x4[8*1024];     // 128KB exchange buffer
  __shared__ float s_pf[16];
  __shared__ float s_rot[NLk*16*4];   // r00,r01,r10,r11 per (layer,qubit)
  __shared__ float s_ent[NLk*15];     // sigmoid(ent)

  float* s_x = (float*)s_x4;          // scalar alias for MLP temps

  const int tid = threadIdx.x;
  const int bid = blockIdx.x;

  if (bid >= 32) {
    // ---------------- Hamiltonian block ----------------
    const int b = bid - 32;
    float* xh = s_x;          // 60
    float* h1 = s_x + 64;     // 256
    float* h2 = s_x + 384;    // 128
    float* h3 = s_x + 512;    // 256
    if (tid < 60) xh[tid] = coords[b*60 + tid];
    __syncthreads();
    if (tid < 256) {
      float acc = hcb1[tid];
      const float* w = hcw1 + tid*60;
      for (int k = 0; k < 60; ++k) acc += w[k]*xh[k];
      h1[tid] = fmaxf(acc, 0.f);
    }
    __syncthreads();
    if (tid < 128) {
      float acc = hcb2[tid];
      const float* w = hcw2 + tid*256;
      for (int k = 0; k < 256; ++k) acc += w[k]*h1[k];
      h2[tid] = fmaxf(acc, 0.f);
    }
    __syncthreads();
    if (tid < 256) {
      float acc = hcb3[tid];
      const float* w = hcw3 + tid*128;
      for (int k = 0; k < 128; ++k) acc += w[k]*h2[k];
      h3[tid] = acc;
    }
    __syncthreads();
    if (tid < 256) {
      float s = 0.f, sq = 0.f;
      for (int k = 0; k < 60; ++k) { float v = xh[k]; s += v; sq += v*v; }
      float mean = s * (1.f/60.f);
      float var  = (sq - 60.f*mean*mean) * (1.f/59.f);
      float freq = sqrtf(1.f/(var + 1e-6f)) * 200.f;
      int i = tid >> 4, j = tid & 15;
      float v = 0.5f*(h3[tid] + h3[j*16 + i]) + ((i==j) ? freq : 0.f);
      out[(size_t)b*OUTSTRIDE + 2*NSTATE + tid] = v;
    }
    return;
  }

  // ---------------- Simulation block ----------------
  const int b    = bid;
  const int lane = tid & 63;
  const int wv   = tid >> 6;

  // Phase 0a: feature-MLP hidden layer (64) + entangler sigmoids (45)
  if (tid < 64) {
    float acc = fpb1[tid];
    const float* w = fpw1 + tid*100;
    const float* f = feats + b*100;
    for (int k = 0; k < 100; ++k) acc += w[k]*f[k];
    s_x[tid] = fmaxf(acc, 0.f);
  } else if (tid < 64+45) {
    int c = tid - 64;
    s_ent[c] = 1.f / (1.f + expf(-entp[c]));
  }
  __syncthreads();
  // Phase 0b: pf = tanh(h1 @ w2^T + b2)
  if (tid < 16) {
    float acc = fpb2[tid];
    const float* w = fpw2 + tid*64;
    for (int k = 0; k < 64; ++k) acc += w[k]*s_x[k];
    s_pf[tid] = tanhf(acc);
  }
  __syncthreads();
  // Phase 0c: rotation matrices (row0=[cxcycz,-sxsysz], row1=[sxsycz,cxcysz])
  if (tid < 48) {                       // tid = layer*16 + q
    float ang = s_pf[tid & 15];
    const float* rp = rotp + tid*3;
    float cx = cosf(0.5f*rp[0]*ang), sx = sinf(0.5f*rp[0]*ang);
    float cy = cosf(0.5f*rp[1]*ang), sy = sinf(0.5f*rp[1]*ang);
    float cz = cosf(0.5f*rp[2]*ang), sz = sinf(0.5f*rp[2]*ang);
    s_rot[tid*4+0] =  cx*cy*cz;
    s_rot[tid*4+1] = -sx*sy*sz;
    s_rot[tid*4+2] =  sx*sy*cz;
    s_rot[tid*4+3] =  cx*cy*sz;
  }
  __syncthreads();

  // State: 64 amplitudes per thread, in registers.
  float a[64];
  #pragma unroll
  for (int i = 0; i < 64; ++i) a[i] = 0.f;
  if (tid == 0) a[0] = 1.f;

  #pragma unroll 1
  for (int lay = 0; lay < NLk; ++lay) {
    const float* rc = s_rot + lay*64;
    // ---- rotations q = 0..15 ----
    #pragma unroll
    for (int q = 0; q < 16; ++q) {
      const float r00 = rc[q*4+0], r01 = rc[q*4+1];
      const float r10 = rc[q*4+2], r11 = rc[q*4+3];
      if (q < 6) {
        // amp bit q lives in lane bits -> wave shuffle
        const int m   = 1 << q;
        const int bit = (lane >> q) & 1;
        const float cown = bit ? r11 : r00;
        const float coth = bit ? r10 : r01;
        #pragma unroll
        for (int i = 0; i < 64; ++i) {
          float o = __shfl_xor(a[i], m, 64);
          a[i] = cown*a[i] + coth*o;
        }
      } else if (q < 12) {
        // amp bit q lives in register index -> local pairs
        const int s = 1 << (q-6);
        #pragma unroll
        for (int i = 0; i < 64; ++i) {
          if (!(i & s)) {
            const int i1 = i | s;
            float a0 = a[i], a1 = a[i1];
            a[i]  = r00*a0 + r01*a1;
            a[i1] = r10*a0 + r11*a1;
          }
        }
      } else {
        // amp bit q lives in wave id -> LDS float4 exchange (2 chunks of 32)
        const int k   = q - 12;
        const int bit = (wv >> k) & 1;
        const float cown = bit ? r11 : r00;
        const float coth = bit ? r10 : r01;
        const int pbase = ((wv ^ (1 << k)) << 6) | lane;
        #pragma unroll
        for (int ch = 0; ch < 2; ++ch) {
          __syncthreads();
          #pragma unroll
          for (int j = 0; j < 8; ++j)
            s_x4[j*1024 + tid] = make_float4(a[ch*32+4*j+0], a[ch*32+4*j+1],
                                             a[ch*32+4*j+2], a[ch*32+4*j+3]);
          __syncthreads();
          #pragma unroll
          for (int j = 0; j < 8; ++j) {
            float4 o = s_x4[j*1024 + pbase];
            a[ch*32+4*j+0] = cown*a[ch*32+4*j+0] + coth*o.x;
            a[ch*32+4*j+1] = cown*a[ch*32+4*j+1] + coth*o.y;
            a[ch*32+4*j+2] = cown*a[ch*32+4*j+2] + coth*o.z;
            a[ch*32+4*j+3] = cown*a[ch*32+4*j+3] + coth*o.w;
          }
        }
      }
    }
    // ---- entanglers c = 0..14 (ctrl=bit c, target=bit c+1) ----
    // new_t = t + p*(other - t) on both sides of the pair, only when ctrl==1
    const float* ec = s_ent + lay*15;
    #pragma unroll
    for (int c = 0; c < 15; ++c) {
      const float p = ec[c];
      if (c < 5) {
        // ctrl lane bit c, target lane bit c+1
        const float pe = ((lane >> c) & 1) ? p : 0.f;
        const int m = 2 << c;
        #pragma unroll
        for (int i = 0; i < 64; ++i) {
          float o = __shfl_xor(a[i], m, 64);
          a[i] += pe*(o - a[i]);
        }
      } else if (c == 5) {
        // ctrl lane bit 5, target reg bit 0
        const float pe = ((lane >> 5) & 1) ? p : 0.f;
        #pragma unroll
        for (int i = 0; i < 64; i += 2) {
          float d = pe*(a[i+1] - a[i]);
          a[i] += d; a[i+1] -= d;
        }
      } else if (c < 11) {
        // ctrl reg bit c-6, target reg bit c-5
        const int cb = 1 << (c-6), tb = 1 << (c-5);
        #pragma unroll
        for (int i = 0; i < 64; ++i) {
          if ((i & cb) && !(i & tb)) {
            const int i1 = i | tb;
            float d = p*(a[i1] - a[i]);
            a[i] += d; a[i1] -= d;
          }
        }
      } else if (c == 11) {
        // ctrl reg bit 5 (elements 32..63 only), target wave bit 0
        const int pbase = ((wv ^ 1) << 6) | lane;
        __syncthreads();
        #pragma unroll
        for (int j = 0; j < 8; ++j)
          s_x4[j*1024 + tid] = make_float4(a[32+4*j+0], a[32+4*j+1],
                                           a[32+4*j+2], a[32+4*j+3]);
        __syncthreads();
        #pragma unroll
        for (int j = 0; j < 8; ++j) {
          float4 o = s_x4[j*1024 + pbase];
          a[32+4*j+0] += p*(o.x - a[32+4*j+0]);
          a[32+4*j+1] += p*(o.y - a[32+4*j+1]);
          a[32+4*j+2] += p*(o.z - a[32+4*j+2]);
          a[32+4*j+3] += p*(o.w - a[32+4*j+3]);
        }
      } else {
        // ctrl wave bit c-12, target wave bit c-11 (pairs share ctrl value)
        const int k  = c - 11;
        const int cb = (wv >> (c-12)) & 1;
        const int pbase = ((wv ^ (1 << k)) << 6) | lane;
        #pragma unroll
        for (int ch = 0; ch < 2; ++ch) {
          __syncthreads();
          if (cb) {
            #pragma unroll
            for (int j = 0; j < 8; ++j)
              s_x4[j*1024 + tid] = make_float4(a[ch*32+4*j+0], a[ch*32+4*j+1],
                                               a[ch*32+4*j+2], a[ch*32+4*j+3]);
          }
          __syncthreads();
          if (cb) {
            #pragma unroll
            for (int j = 0; j < 8; ++j) {
              float4 o = s_x4[j*1024 + pbase];
              a[ch*32+4*j+0] += p*(o.x - a[ch*32+4*j+0]);
              a[ch*32+4*j+1] += p*(o.y - a[ch*32+4*j+1]);
              a[ch*32+4*j+2] += p*(o.z - a[ch*32+4*j+2]);
              a[ch*32+4*j+3] += p*(o.w - a[ch*32+4*j+3]);
            }
          }
        }
      }
    }
  }

  // ---- epilogue: real amps + zero imag (state is provably real) ----
  {
    float* orr = out + (size_t)b*OUTSTRIDE;
    const int base = (wv << 12) | lane;
    #pragma unroll
    for (int i = 0; i < 64; ++i)
      orr[base + (i<<6)] = a[i];        // coalesced dword per wave
    // imag half: contiguous float4 zero-fill, decoupled from state layout
    float4* oz = (float4*)(orr + NSTATE);
    const float4 z4 = make_float4(0.f, 0.f, 0.f, 0.f);
    #pragma unroll
    for (int k = 0; k < 16; ++k)
      oz[k*1024 + tid] = z4;
  }
}

extern "C" void kernel_launch(void* const* d_in, const int* in_sizes, int n_in,
                              void* d_out, int out_size, void* d_ws, size_t ws_size,
                              hipStream_t stream) {
  vqe_fused<<<dim3(64), dim3(1024), 0, stream>>>(
      (const float*)d_in[0],  (const float*)d_in[1],
      (const float*)d_in[2],  (const float*)d_in[3],
      (const float*)d_in[4],  (const float*)d_in[5],
      (const float*)d_in[6],  (const float*)d_in[7],
      (const float*)d_in[8],  (const float*)d_in[9],
      (const float*)d_in[10], (const float*)d_in[11],
      (const float*)d_in[12], (const float*)d_in[13],
      (float*)d_out);
}

// Round 3
// 265.417 us; speedup vs baseline: 1.7923x; 1.0053x over previous
//
#include <hip/hip_runtime.h>
#include <math.h>

#define NLk 3
#define NSTATE 65536          // 2^16
#define OUTSTRIDE 131328      // 2*65536 + 256

// One kernel, 64 blocks x 1024 threads.
//  blocks 0..31  : state-vector simulation for batch b (state held in registers)
//  blocks 32..63 : Hamiltonian MLP for batch b-32
// State mapping (sim blocks): amp index A = (wv<<12) | (reg<<6) | lane
//   bits 0..5  = lane      -> gates via __shfl_xor
//   bits 6..11 = reg index -> gates in registers
//   bits 12..15= wave id   -> gates via LDS exchange (128KB float4 buffer, 2 chunks)
// amdgpu_waves_per_eu(4,4): 129KB LDS caps us at 1 WG/CU = 4 waves/EU anyway;
// pinning MAX waves/EU to 4 gives the register allocator the full 128-VGPR
// budget. R1/R2 evidence: __launch_bounds__(1024,4) still allocated 64 VGPRs
// and spilled the 64-float state (8.4MB spill stores + 5.9MB reloads per
// dispatch = the entire perf gap).
__global__ __attribute__((amdgpu_flat_work_group_size(1024,1024)))
__attribute__((amdgpu_waves_per_eu(4,4))) void vqe_fused(
    const float* __restrict__ coords, const float* __restrict__ feats,
    const float* __restrict__ rotp,   const float* __restrict__ entp,
    const float* __restrict__ fpw1,   const float* __restrict__ fpb1,
    const float* __restrict__ fpw2,   const float* __restrict__ fpb2,
    const float* __restrict__ hcw1,   const float* __restrict__ hcb1,
    const float* __restrict__ hcw2,   const float* __restrict__ hcb2,
    const float* __restrict__ hcw3,   const float* __restrict__ hcb3,
    float* __restrict__ out)
{
  __shared__ float4 s_x4[8*1024];     // 128KB exchange buffer
  __shared__ float s_pf[16];
  __shared__ float s_rot[NLk*16*4];   // r00,r01,r10,r11 per (layer,qubit)
  __shared__ float s_ent[NLk*15];     // sigmoid(ent)

  float* s_x = (float*)s_x4;          // scalar alias for MLP temps

  const int tid = threadIdx.x;
  const int bid = blockIdx.x;

  if (bid >= 32) {
    // ---------------- Hamiltonian block ----------------
    const int b = bid - 32;
    float* xh = s_x;          // 60
    float* h1 = s_x + 64;     // 256
    float* h2 = s_x + 384;    // 128
    float* h3 = s_x + 512;    // 256
    if (tid < 60) xh[tid] = coords[b*60 + tid];
    __syncthreads();
    if (tid < 256) {
      float acc = hcb1[tid];
      const float* w = hcw1 + tid*60;
      for (int k = 0; k < 60; ++k) acc += w[k]*xh[k];
      h1[tid] = fmaxf(acc, 0.f);
    }
    __syncthreads();
    if (tid < 128) {
      float acc = hcb2[tid];
      const float* w = hcw2 + tid*256;
      for (int k = 0; k < 256; ++k) acc += w[k]*h1[k];
      h2[tid] = fmaxf(acc, 0.f);
    }
    __syncthreads();
    if (tid < 256) {
      float acc = hcb3[tid];
      const float* w = hcw3 + tid*128;
      for (int k = 0; k < 128; ++k) acc += w[k]*h2[k];
      h3[tid] = acc;
    }
    __syncthreads();
    if (tid < 256) {
      float s = 0.f, sq = 0.f;
      for (int k = 0; k < 60; ++k) { float v = xh[k]; s += v; sq += v*v; }
      float mean = s * (1.f/60.f);
      float var  = (sq - 60.f*mean*mean) * (1.f/59.f);
      float freq = sqrtf(1.f/(var + 1e-6f)) * 200.f;
      int i = tid >> 4, j = tid & 15;
      float v = 0.5f*(h3[tid] + h3[j*16 + i]) + ((i==j) ? freq : 0.f);
      out[(size_t)b*OUTSTRIDE + 2*NSTATE + tid] = v;
    }
    return;
  }

  // ---------------- Simulation block ----------------
  const int b    = bid;
  const int lane = tid & 63;
  const int wv   = tid >> 6;

  // Phase 0a: feature-MLP hidden layer (64) + entangler sigmoids (45)
  if (tid < 64) {
    float acc = fpb1[tid];
    const float* w = fpw1 + tid*100;
    const float* f = feats + b*100;
    for (int k = 0; k < 100; ++k) acc += w[k]*f[k];
    s_x[tid] = fmaxf(acc, 0.f);
  } else if (tid < 64+45) {
    int c = tid - 64;
    s_ent[c] = 1.f / (1.f + expf(-entp[c]));
  }
  __syncthreads();
  // Phase 0b: pf = tanh(h1 @ w2^T + b2)
  if (tid < 16) {
    float acc = fpb2[tid];
    const float* w = fpw2 + tid*64;
    for (int k = 0; k < 64; ++k) acc += w[k]*s_x[k];
    s_pf[tid] = tanhf(acc);
  }
  __syncthreads();
  // Phase 0c: rotation matrices (row0=[cxcycz,-sxsysz], row1=[sxsycz,cxcysz])
  if (tid < 48) {                       // tid = layer*16 + q
    float ang = s_pf[tid & 15];
    const float* rp = rotp + tid*3;
    float cx = cosf(0.5f*rp[0]*ang), sx = sinf(0.5f*rp[0]*ang);
    float cy = cosf(0.5f*rp[1]*ang), sy = sinf(0.5f*rp[1]*ang);
    float cz = cosf(0.5f*rp[2]*ang), sz = sinf(0.5f*rp[2]*ang);
    s_rot[tid*4+0] =  cx*cy*cz;
    s_rot[tid*4+1] = -sx*sy*sz;
    s_rot[tid*4+2] =  sx*sy*cz;
    s_rot[tid*4+3] =  cx*cy*sz;
  }
  __syncthreads();

  // State: 64 amplitudes per thread, in registers.
  float a[64];
  #pragma unroll
  for (int i = 0; i < 64; ++i) a[i] = 0.f;
  if (tid == 0) a[0] = 1.f;

  #pragma unroll 1
  for (int lay = 0; lay < NLk; ++lay) {
    const float* rc = s_rot + lay*64;
    // ---- rotations q = 0..15 ----
    #pragma unroll
    for (int q = 0; q < 16; ++q) {
      const float r00 = rc[q*4+0], r01 = rc[q*4+1];
      const float r10 = rc[q*4+2], r11 = rc[q*4+3];
      if (q < 6) {
        // amp bit q lives in lane bits -> wave shuffle
        const int m   = 1 << q;
        const int bit = (lane >> q) & 1;
        const float cown = bit ? r11 : r00;
        const float coth = bit ? r10 : r01;
        #pragma unroll
        for (int i = 0; i < 64; ++i) {
          float o = __shfl_xor(a[i], m, 64);
          a[i] = cown*a[i] + coth*o;
        }
      } else if (q < 12) {
        // amp bit q lives in register index -> local pairs
        const int s = 1 << (q-6);
        #pragma unroll
        for (int i = 0; i < 64; ++i) {
          if (!(i & s)) {
            const int i1 = i | s;
            float a0 = a[i], a1 = a[i1];
            a[i]  = r00*a0 + r01*a1;
            a[i1] = r10*a0 + r11*a1;
          }
        }
      } else {
        // amp bit q lives in wave id -> LDS float4 exchange (2 chunks of 32)
        const int k   = q - 12;
        const int bit = (wv >> k) & 1;
        const float cown = bit ? r11 : r00;
        const float coth = bit ? r10 : r01;
        const int pbase = ((wv ^ (1 << k)) << 6) | lane;
        #pragma unroll
        for (int ch = 0; ch < 2; ++ch) {
          __syncthreads();
          #pragma unroll
          for (int j = 0; j < 8; ++j)
            s_x4[j*1024 + tid] = make_float4(a[ch*32+4*j+0], a[ch*32+4*j+1],
                                             a[ch*32+4*j+2], a[ch*32+4*j+3]);
          __syncthreads();
          #pragma unroll
          for (int j = 0; j < 8; ++j) {
            float4 o = s_x4[j*1024 + pbase];
            a[ch*32+4*j+0] = cown*a[ch*32+4*j+0] + coth*o.x;
            a[ch*32+4*j+1] = cown*a[ch*32+4*j+1] + coth*o.y;
            a[ch*32+4*j+2] = cown*a[ch*32+4*j+2] + coth*o.z;
            a[ch*32+4*j+3] = cown*a[ch*32+4*j+3] + coth*o.w;
          }
        }
      }
    }
    // ---- entanglers c = 0..14 (ctrl=bit c, target=bit c+1) ----
    // new_t = t + p*(other - t) on both sides of the pair, only when ctrl==1
    const float* ec = s_ent + lay*15;
    #pragma unroll
    for (int c = 0; c < 15; ++c) {
      const float p = ec[c];
      if (c < 5) {
        // ctrl lane bit c, target lane bit c+1
        const float pe = ((lane >> c) & 1) ? p : 0.f;
        const int m = 2 << c;
        #pragma unroll
        for (int i = 0; i < 64; ++i) {
          float o = __shfl_xor(a[i], m, 64);
          a[i] += pe*(o - a[i]);
        }
      } else if (c == 5) {
        // ctrl lane bit 5, target reg bit 0
        const float pe = ((lane >> 5) & 1) ? p : 0.f;
        #pragma unroll
        for (int i = 0; i < 64; i += 2) {
          float d = pe*(a[i+1] - a[i]);
          a[i] += d; a[i+1] -= d;
        }
      } else if (c < 11) {
        // ctrl reg bit c-6, target reg bit c-5
        const int cb = 1 << (c-6), tb = 1 << (c-5);
        #pragma unroll
        for (int i = 0; i < 64; ++i) {
          if ((i & cb) && !(i & tb)) {
            const int i1 = i | tb;
            float d = p*(a[i1] - a[i]);
            a[i] += d; a[i1] -= d;
          }
        }
      } else if (c == 11) {
        // ctrl reg bit 5 (elements 32..63 only), target wave bit 0
        const int pbase = ((wv ^ 1) << 6) | lane;
        __syncthreads();
        #pragma unroll
        for (int j = 0; j < 8; ++j)
          s_x4[j*1024 + tid] = make_float4(a[32+4*j+0], a[32+4*j+1],
                                           a[32+4*j+2], a[32+4*j+3]);
        __syncthreads();
        #pragma unroll
        for (int j = 0; j < 8; ++j) {
          float4 o = s_x4[j*1024 + pbase];
          a[32+4*j+0] += p*(o.x - a[32+4*j+0]);
          a[32+4*j+1] += p*(o.y - a[32+4*j+1]);
          a[32+4*j+2] += p*(o.z - a[32+4*j+2]);
          a[32+4*j+3] += p*(o.w - a[32+4*j+3]);
        }
      } else {
        // ctrl wave bit c-12, target wave bit c-11 (pairs share ctrl value)
        const int k  = c - 11;
        const int cb = (wv >> (c-12)) & 1;
        const int pbase = ((wv ^ (1 << k)) << 6) | lane;
        #pragma unroll
        for (int ch = 0; ch < 2; ++ch) {
          __syncthreads();
          if (cb) {
            #pragma unroll
            for (int j = 0; j < 8; ++j)
              s_x4[j*1024 + tid] = make_float4(a[ch*32+4*j+0], a[ch*32+4*j+1],
                                               a[ch*32+4*j+2], a[ch*32+4*j+3]);
          }
          __syncthreads();
          if (cb) {
            #pragma unroll
            for (int j = 0; j < 8; ++j) {
              float4 o = s_x4[j*1024 + pbase];
              a[ch*32+4*j+0] += p*(o.x - a[ch*32+4*j+0]);
              a[ch*32+4*j+1] += p*(o.y - a[ch*32+4*j+1]);
              a[ch*32+4*j+2] += p*(o.z - a[ch*32+4*j+2]);
              a[ch*32+4*j+3] += p*(o.w - a[ch*32+4*j+3]);
            }
          }
        }
      }
    }
  }

  // ---- epilogue: real amps + zero imag (state is provably real) ----
  {
    float* orr = out + (size_t)b*OUTSTRIDE;
    const int base = (wv << 12) | lane;
    #pragma unroll
    for (int i = 0; i < 64; ++i)
      orr[base + (i<<6)] = a[i];        // coalesced dword per wave
    // imag half: contiguous float4 zero-fill, decoupled from state layout
    float4* oz = (float4*)(orr + NSTATE);
    const float4 z4 = make_float4(0.f, 0.f, 0.f, 0.f);
    #pragma unroll
    for (int k = 0; k < 16; ++k)
      oz[k*1024 + tid] = z4;
  }
}

extern "C" void kernel_launch(void* const* d_in, const int* in_sizes, int n_in,
                              void* d_out, int out_size, void* d_ws, size_t ws_size,
                              hipStream_t stream) {
  vqe_fused<<<dim3(64), dim3(1024), 0, stream>>>(
      (const float*)d_in[0],  (const float*)d_in[1],
      (const float*)d_in[2],  (const float*)d_in[3],
      (const float*)d_in[4],  (const float*)d_in[5],
      (const float*)d_in[6],  (const float*)d_in[7],
      (const float*)d_in[8],  (const float*)d_in[9],
      (const float*)d_in[10], (const float*)d_in[11],
      (const float*)d_in[12], (const float*)d_in[13],
      (float*)d_out);
}

// Round 4
// 258.285 us; speedup vs baseline: 1.8418x; 1.0276x over previous
//
#include <hip/hip_runtime.h>
#include <math.h>

#define NLk 3
#define NSTATE 65536          // 2^16
#define OUTSTRIDE 131328      // 2*65536 + 256

// One kernel, 64 blocks x 1024 threads.
//  blocks 0..31  : state-vector simulation for batch b (state held in registers)
//  blocks 32..63 : Hamiltonian MLP for batch b-32
// State mapping (sim blocks): amp index A = (wv<<12) | (reg<<6) | lane
//   bits 0..5  = lane      -> gates via __shfl_xor
//   bits 6..11 = reg index -> gates in registers (compile-time indices ONLY)
//   bits 12..15= wave id   -> gates via LDS exchange (128KB float4 buffer)
//
// R3 lesson: the runtime q/c gate loops were not fully unrolled, so register-
// bit gates indexed a[] with runtime masks -> the whole state array was
// demoted to scratch (VGPR_Count stuck at 64, 14MB/dispatch scratch traffic).
// Every gate is now a template<int> with constexpr masks so a[] can only be
// indexed by literals.

template<int Q>
__device__ __forceinline__ void rot_gate(float (&a)[64], const float* __restrict__ rc,
                                         int lane, int wv, int tid, float4* s_x4) {
  const float r00 = rc[Q*4+0], r01 = rc[Q*4+1];
  const float r10 = rc[Q*4+2], r11 = rc[Q*4+3];
  if constexpr (Q < 6) {
    // amp bit Q in lane bits -> wave shuffle
    constexpr int m = 1 << Q;
    const int bit = (lane >> Q) & 1;
    const float cown = bit ? r11 : r00;
    const float coth = bit ? r10 : r01;
    #pragma unroll
    for (int i = 0; i < 64; ++i) {
      float o = __shfl_xor(a[i], m, 64);
      a[i] = cown*a[i] + coth*o;
    }
  } else if constexpr (Q < 12) {
    // amp bit Q in register index -> local pairs, constexpr stride
    constexpr int s = 1 << (Q-6);
    #pragma unroll
    for (int i = 0; i < 64; ++i) {
      if constexpr (true) {
        if ((i & s) == 0) {
          const int i1 = i | s;
          float a0 = a[i], a1 = a[i1];
          a[i]  = r00*a0 + r01*a1;
          a[i1] = r10*a0 + r11*a1;
        }
      }
    }
  } else {
    // amp bit Q in wave id -> LDS exchange, 2 chunks of 32
    constexpr int k = Q - 12;
    const int bit = (wv >> k) & 1;
    const float cown = bit ? r11 : r00;
    const float coth = bit ? r10 : r01;
    const int pbase = ((wv ^ (1 << k)) << 6) | lane;
    // chunk 0 (regs 0..31)
    __syncthreads();
    #pragma unroll
    for (int j = 0; j < 8; ++j)
      s_x4[j*1024 + tid] = make_float4(a[4*j+0], a[4*j+1], a[4*j+2], a[4*j+3]);
    __syncthreads();
    #pragma unroll
    for (int j = 0; j < 8; ++j) {
      float4 o = s_x4[j*1024 + pbase];
      a[4*j+0] = cown*a[4*j+0] + coth*o.x;
      a[4*j+1] = cown*a[4*j+1] + coth*o.y;
      a[4*j+2] = cown*a[4*j+2] + coth*o.z;
      a[4*j+3] = cown*a[4*j+3] + coth*o.w;
    }
    // chunk 1 (regs 32..63)
    __syncthreads();
    #pragma unroll
    for (int j = 0; j < 8; ++j)
      s_x4[j*1024 + tid] = make_float4(a[32+4*j+0], a[32+4*j+1], a[32+4*j+2], a[32+4*j+3]);
    __syncthreads();
    #pragma unroll
    for (int j = 0; j < 8; ++j) {
      float4 o = s_x4[j*1024 + pbase];
      a[32+4*j+0] = cown*a[32+4*j+0] + coth*o.x;
      a[32+4*j+1] = cown*a[32+4*j+1] + coth*o.y;
      a[32+4*j+2] = cown*a[32+4*j+2] + coth*o.z;
      a[32+4*j+3] = cown*a[32+4*j+3] + coth*o.w;
    }
  }
}

template<int C>
__device__ __forceinline__ void ent_gate(float (&a)[64], float p,
                                         int lane, int wv, int tid, float4* s_x4) {
  if constexpr (C < 5) {
    // ctrl lane bit C, target lane bit C+1
    const float pe = ((lane >> C) & 1) ? p : 0.f;
    constexpr int m = 2 << C;
    #pragma unroll
    for (int i = 0; i < 64; ++i) {
      float o = __shfl_xor(a[i], m, 64);
      a[i] += pe*(o - a[i]);
    }
  } else if constexpr (C == 5) {
    // ctrl lane bit 5, target reg bit 0
    const float pe = ((lane >> 5) & 1) ? p : 0.f;
    #pragma unroll
    for (int i = 0; i < 64; i += 2) {
      float d = pe*(a[i+1] - a[i]);
      a[i] += d; a[i+1] -= d;
    }
  } else if constexpr (C < 11) {
    // ctrl reg bit C-6, target reg bit C-5 (constexpr masks)
    constexpr int cb = 1 << (C-6), tb = 1 << (C-5);
    #pragma unroll
    for (int i = 0; i < 64; ++i) {
      if ((i & cb) != 0 && (i & tb) == 0) {
        const int i1 = i | tb;
        float d = p*(a[i1] - a[i]);
        a[i] += d; a[i1] -= d;
      }
    }
  } else if constexpr (C == 11) {
    // ctrl reg bit 5 (elements 32..63), target wave bit 0
    const int pbase = ((wv ^ 1) << 6) | lane;
    __syncthreads();
    #pragma unroll
    for (int j = 0; j < 8; ++j)
      s_x4[j*1024 + tid] = make_float4(a[32+4*j+0], a[32+4*j+1], a[32+4*j+2], a[32+4*j+3]);
    __syncthreads();
    #pragma unroll
    for (int j = 0; j < 8; ++j) {
      float4 o = s_x4[j*1024 + pbase];
      a[32+4*j+0] += p*(o.x - a[32+4*j+0]);
      a[32+4*j+1] += p*(o.y - a[32+4*j+1]);
      a[32+4*j+2] += p*(o.z - a[32+4*j+2]);
      a[32+4*j+3] += p*(o.w - a[32+4*j+3]);
    }
  } else {
    // ctrl wave bit C-12, target wave bit C-11 (pairs share ctrl value)
    constexpr int k = C - 11;
    const int cbv = (wv >> (C-12)) & 1;
    const int pbase = ((wv ^ (1 << k)) << 6) | lane;
    // chunk 0
    __syncthreads();
    if (cbv) {
      #pragma unroll
      for (int j = 0; j < 8; ++j)
        s_x4[j*1024 + tid] = make_float4(a[4*j+0], a[4*j+1], a[4*j+2], a[4*j+3]);
    }
    __syncthreads();
    if (cbv) {
      #pragma unroll
      for (int j = 0; j < 8; ++j) {
        float4 o = s_x4[j*1024 + pbase];
        a[4*j+0] += p*(o.x - a[4*j+0]);
        a[4*j+1] += p*(o.y - a[4*j+1]);
        a[4*j+2] += p*(o.z - a[4*j+2]);
        a[4*j+3] += p*(o.w - a[4*j+3]);
      }
    }
    // chunk 1
    __syncthreads();
    if (cbv) {
      #pragma unroll
      for (int j = 0; j < 8; ++j)
        s_x4[j*1024 + tid] = make_float4(a[32+4*j+0], a[32+4*j+1], a[32+4*j+2], a[32+4*j+3]);
    }
    __syncthreads();
    if (cbv) {
      #pragma unroll
      for (int j = 0; j < 8; ++j) {
        float4 o = s_x4[j*1024 + pbase];
        a[32+4*j+0] += p*(o.x - a[32+4*j+0]);
        a[32+4*j+1] += p*(o.y - a[32+4*j+1]);
        a[32+4*j+2] += p*(o.z - a[32+4*j+2]);
        a[32+4*j+3] += p*(o.w - a[32+4*j+3]);
      }
    }
  }
}

__global__ __attribute__((amdgpu_flat_work_group_size(1024,1024)))
__attribute__((amdgpu_waves_per_eu(4,4))) void vqe_fused(
    const float* __restrict__ coords, const float* __restrict__ feats,
    const float* __restrict__ rotp,   const float* __restrict__ entp,
    const float* __restrict__ fpw1,   const float* __restrict__ fpb1,
    const float* __restrict__ fpw2,   const float* __restrict__ fpb2,
    const float* __restrict__ hcw1,   const float* __restrict__ hcb1,
    const float* __restrict__ hcw2,   const float* __restrict__ hcb2,
    const float* __restrict__ hcw3,   const float* __restrict__ hcb3,
    float* __restrict__ out)
{
  __shared__ float4 s_x4[8*1024];     // 128KB exchange buffer
  __shared__ float s_pf[16];
  __shared__ float s_rot[NLk*16*4];   // r00,r01,r10,r11 per (layer,qubit)
  __shared__ float s_ent[NLk*15];     // sigmoid(ent)

  float* s_x = (float*)s_x4;          // scalar alias for MLP temps

  const int tid = threadIdx.x;
  const int bid = blockIdx.x;

  if (bid >= 32) {
    // ---------------- Hamiltonian block ----------------
    const int b = bid - 32;
    float* xh = s_x;          // 60
    float* h1 = s_x + 64;     // 256
    float* h2 = s_x + 384;    // 128
    float* h3 = s_x + 512;    // 256
    if (tid < 60) xh[tid] = coords[b*60 + tid];
    __syncthreads();
    if (tid < 256) {
      float acc = hcb1[tid];
      const float* w = hcw1 + tid*60;
      for (int k = 0; k < 60; ++k) acc += w[k]*xh[k];
      h1[tid] = fmaxf(acc, 0.f);
    }
    __syncthreads();
    if (tid < 128) {
      float acc = hcb2[tid];
      const float* w = hcw2 + tid*256;
      for (int k = 0; k < 256; ++k) acc += w[k]*h1[k];
      h2[tid] = fmaxf(acc, 0.f);
    }
    __syncthreads();
    if (tid < 256) {
      float acc = hcb3[tid];
      const float* w = hcw3 + tid*128;
      for (int k = 0; k < 128; ++k) acc += w[k]*h2[k];
      h3[tid] = acc;
    }
    __syncthreads();
    if (tid < 256) {
      float s = 0.f, sq = 0.f;
      for (int k = 0; k < 60; ++k) { float v = xh[k]; s += v; sq += v*v; }
      float mean = s * (1.f/60.f);
      float var  = (sq - 60.f*mean*mean) * (1.f/59.f);
      float freq = sqrtf(1.f/(var + 1e-6f)) * 200.f;
      int i = tid >> 4, j = tid & 15;
      float v = 0.5f*(h3[tid] + h3[j*16 + i]) + ((i==j) ? freq : 0.f);
      out[(size_t)b*OUTSTRIDE + 2*NSTATE + tid] = v;
    }
    return;
  }

  // ---------------- Simulation block ----------------
  const int b    = bid;
  const int lane = tid & 63;
  const int wv   = tid >> 6;

  // Phase 0a: feature-MLP hidden layer (64) + entangler sigmoids (45)
  if (tid < 64) {
    float acc = fpb1[tid];
    const float* w = fpw1 + tid*100;
    const float* f = feats + b*100;
    for (int k = 0; k < 100; ++k) acc += w[k]*f[k];
    s_x[tid] = fmaxf(acc, 0.f);
  } else if (tid < 64+45) {
    int c = tid - 64;
    s_ent[c] = 1.f / (1.f + expf(-entp[c]));
  }
  __syncthreads();
  // Phase 0b: pf = tanh(h1 @ w2^T + b2)
  if (tid < 16) {
    float acc = fpb2[tid];
    const float* w = fpw2 + tid*64;
    for (int k = 0; k < 64; ++k) acc += w[k]*s_x[k];
    s_pf[tid] = tanhf(acc);
  }
  __syncthreads();
  // Phase 0c: rotation matrices (row0=[cxcycz,-sxsysz], row1=[sxsycz,cxcysz])
  if (tid < 48) {                       // tid = layer*16 + q
    float ang = s_pf[tid & 15];
    const float* rp = rotp + tid*3;
    float cx = cosf(0.5f*rp[0]*ang), sx = sinf(0.5f*rp[0]*ang);
    float cy = cosf(0.5f*rp[1]*ang), sy = sinf(0.5f*rp[1]*ang);
    float cz = cosf(0.5f*rp[2]*ang), sz = sinf(0.5f*rp[2]*ang);
    s_rot[tid*4+0] =  cx*cy*cz;
    s_rot[tid*4+1] = -sx*sy*sz;
    s_rot[tid*4+2] =  sx*sy*cz;
    s_rot[tid*4+3] =  cx*cy*sz;
  }
  __syncthreads();

  // State: 64 amplitudes per thread, in registers (literal indices only).
  float a[64];
  #pragma unroll
  for (int i = 0; i < 64; ++i) a[i] = 0.f;
  if (tid == 0) a[0] = 1.f;

  #pragma unroll 1
  for (int lay = 0; lay < NLk; ++lay) {
    const float* rc = s_rot + lay*64;
    rot_gate< 0>(a, rc, lane, wv, tid, s_x4);
    rot_gate< 1>(a, rc, lane, wv, tid, s_x4);
    rot_gate< 2>(a, rc, lane, wv, tid, s_x4);
    rot_gate< 3>(a, rc, lane, wv, tid, s_x4);
    rot_gate< 4>(a, rc, lane, wv, tid, s_x4);
    rot_gate< 5>(a, rc, lane, wv, tid, s_x4);
    rot_gate< 6>(a, rc, lane, wv, tid, s_x4);
    rot_gate< 7>(a, rc, lane, wv, tid, s_x4);
    rot_gate< 8>(a, rc, lane, wv, tid, s_x4);
    rot_gate< 9>(a, rc, lane, wv, tid, s_x4);
    rot_gate<10>(a, rc, lane, wv, tid, s_x4);
    rot_gate<11>(a, rc, lane, wv, tid, s_x4);
    rot_gate<12>(a, rc, lane, wv, tid, s_x4);
    rot_gate<13>(a, rc, lane, wv, tid, s_x4);
    rot_gate<14>(a, rc, lane, wv, tid, s_x4);
    rot_gate<15>(a, rc, lane, wv, tid, s_x4);
    const float* ec = s_ent + lay*15;
    ent_gate< 0>(a, ec[ 0], lane, wv, tid, s_x4);
    ent_gate< 1>(a, ec[ 1], lane, wv, tid, s_x4);
    ent_gate< 2>(a, ec[ 2], lane, wv, tid, s_x4);
    ent_gate< 3>(a, ec[ 3], lane, wv, tid, s_x4);
    ent_gate< 4>(a, ec[ 4], lane, wv, tid, s_x4);
    ent_gate< 5>(a, ec[ 5], lane, wv, tid, s_x4);
    ent_gate< 6>(a, ec[ 6], lane, wv, tid, s_x4);
    ent_gate< 7>(a, ec[ 7], lane, wv, tid, s_x4);
    ent_gate< 8>(a, ec[ 8], lane, wv, tid, s_x4);
    ent_gate< 9>(a, ec[ 9], lane, wv, tid, s_x4);
    ent_gate<10>(a, ec[10], lane, wv, tid, s_x4);
    ent_gate<11>(a, ec[11], lane, wv, tid, s_x4);
    ent_gate<12>(a, ec[12], lane, wv, tid, s_x4);
    ent_gate<13>(a, ec[13], lane, wv, tid, s_x4);
    ent_gate<14>(a, ec[14], lane, wv, tid, s_x4);
  }

  // ---- epilogue: real amps + zero imag (state is provably real) ----
  {
    float* orr = out + (size_t)b*OUTSTRIDE;
    const int base = (wv << 12) | lane;
    #pragma unroll
    for (int i = 0; i < 64; ++i)
      orr[base + (i<<6)] = a[i];        // coalesced dword per wave
    // imag half: contiguous float4 zero-fill, decoupled from state layout
    float4* oz = (float4*)(orr + NSTATE);
    const float4 z4 = make_float4(0.f, 0.f, 0.f, 0.f);
    #pragma unroll
    for (int k = 0; k < 16; ++k)
      oz[k*1024 + tid] = z4;
  }
}

extern "C" void kernel_launch(void* const* d_in, const int* in_sizes, int n_in,
                              void* d_out, int out_size, void* d_ws, size_t ws_size,
                              hipStream_t stream) {
  vqe_fused<<<dim3(64), dim3(1024), 0, stream>>>(
      (const float*)d_in[0],  (const float*)d_in[1],
      (const float*)d_in[2],  (const float*)d_in[3],
      (const float*)d_in[4],  (const float*)d_in[5],
      (const float*)d_in[6],  (const float*)d_in[7],
      (const float*)d_in[8],  (const float*)d_in[9],
      (const float*)d_in[10], (const float*)d_in[11],
      (const float*)d_in[12], (const float*)d_in[13],
      (float*)d_out);
}